// Round 13
// baseline (114.174 us; speedup 1.0000x reference)
//
#include <hip/hip_runtime.h>
#include <math.h>

#define NPATCH 128
#define CH 8              // channels per patch = L / N_PATCHES
#define D 64
#define G 8               // query patches per tile
#define NQ (G*CH)         // 64 queries/tile
#define NKEY 128          // key-window slots per tile
#define VSTR 136          // f16 strides: ≡ 4 (mod 8) dwords -> 2-way max aliasing
#define PSTR 100          // per-wave-relative P row: 96 keys + pad
#define TPB 8             // tiles per persistent block

typedef __fp16 half8 __attribute__((ext_vector_type(8)));
typedef float  f32x4 __attribute__((ext_vector_type(4)));
typedef unsigned u32x4 __attribute__((ext_vector_type(4)));

static __device__ __forceinline__ unsigned pk(float x, float y) {
    return __builtin_bit_cast(unsigned, __builtin_amdgcn_cvt_pkrtz(x, y));
}
static __device__ __forceinline__ half8 ld8(const unsigned short* p) {
    return __builtin_bit_cast(half8, *(const u32x4*)p);
}
static __device__ __forceinline__ half8 mk8(const float4& a, const float4& b) {
    u32x4 u = { pk(a.x, a.y), pk(a.z, a.w), pk(b.x, b.y), pk(b.z, b.w) };
    return __builtin_bit_cast(half8, u);
}

__global__ __launch_bounds__(256) void signed_attn_kernel(
    const float* __restrict__ Q, const float* __restrict__ K,
    const float* __restrict__ V, const float* __restrict__ logscale,
    float* __restrict__ O)
{
    __shared__ __align__(16) unsigned short sVt[2][D * VSTR]; // 2 x 17408 B (double buffer)
    __shared__ __align__(16) unsigned short sP[NQ * PSTR];    // 12800 B (wave-private rows)
    // total 47616 B -> 2 blocks/CU

    const int tid = threadIdx.x;
    const int wav = tid >> 6, lane = tid & 63;
    const int col = lane & 15, quad = lane >> 4;

    const float scale = fminf(fmaxf(__expf(logscale[0]), 1.0f), 30.0f) * 0.125f;

    // zero sP pad (rel cols 80..95) once; softmax only writes cols 0..79
#pragma unroll
    for (int r = 0; r < 4; ++r) {
        const int q = wav * 16 + quad * 4 + r;
        sP[q * PSTR + 80 + col] = 0;
    }

    int tile = blockIdx.x * TPB;              // 8 consecutive tiles (50% K/V window overlap)

    long long qb, kb; int nst;
    {
        const int bh = tile >> 4, p0 = (tile & 15) * G;
        const long long base = (long long)bh * (NPATCH * CH) * D;
        qb = base + (long long)(p0 * CH) * D;
        kb = base + (long long)((p0 + 1) * CH) * D;
        nst = min(NKEY, (NPATCH - 1 - p0) * CH);
    }

    float4 qr[4], kf[5][4], va[4], vb[4];

    // ---- head: issue tile-0 loads ----
    {
        const float4* Qg4 = (const float4*)(Q + qb) + (long long)(wav * 16 + col) * 16;
        qr[0] = Qg4[quad * 2];     qr[1] = Qg4[quad * 2 + 1];
        qr[2] = Qg4[8 + quad * 2]; qr[3] = Qg4[9 + quad * 2];
        const float4* Kg4 = (const float4*)(K + kb);
#pragma unroll
        for (int t = 0; t < 5; ++t) {
            const int krel = (wav + t) * 16 + col;
            const float4* Kr = Kg4 + ((krel < nst) ? krel : (nst - 1)) * 16;
            kf[t][0] = Kr[quad * 2];     kf[t][1] = Kr[quad * 2 + 1];
            kf[t][2] = Kr[8 + quad * 2]; kf[t][3] = Kr[9 + quad * 2];
        }
        const float4* Vg = (const float4*)(V + kb);
#pragma unroll
        for (int it = 0; it < 4; ++it) {
            const int u = tid + it * 256, kp = u & 63, dq = u >> 6;
            va[it] = make_float4(0.f, 0.f, 0.f, 0.f); vb[it] = va[it];
            if (2 * kp < nst) { va[it] = Vg[(2 * kp) * 16 + dq]; vb[it] = Vg[(2 * kp + 1) * 16 + dq]; }
        }
    }

    int buf = 0;
    for (int t = 0; t < TPB; ++t) {
        const long long qb_c = qb;
        const int nst_c = nst;

        // ---- 1. V regs (landed) -> sVt[buf] ----
        unsigned short* vt = sVt[buf];
#pragma unroll
        for (int it = 0; it < 4; ++it) {
            const int u = tid + it * 256, kp = u & 63, dq = u >> 6;
            *(unsigned*)&vt[(dq * 4 + 0) * VSTR + 2 * kp] = pk(va[it].x, vb[it].x);
            *(unsigned*)&vt[(dq * 4 + 1) * VSTR + 2 * kp] = pk(va[it].y, vb[it].y);
            *(unsigned*)&vt[(dq * 4 + 2) * VSTR + 2 * kp] = pk(va[it].z, vb[it].z);
            *(unsigned*)&vt[(dq * 4 + 3) * VSTR + 2 * kp] = pk(va[it].w, vb[it].w);
        }

        // ---- next-tile bookkeeping; issue V prefetch (va/vb just freed) ----
        const int nxt = (t == TPB - 1) ? tile : tile + 1;
        {
            const int bh = nxt >> 4, p0 = (nxt & 15) * G;
            const long long base = (long long)bh * (NPATCH * CH) * D;
            qb = base + (long long)(p0 * CH) * D;
            kb = base + (long long)((p0 + 1) * CH) * D;
            nst = min(NKEY, (NPATCH - 1 - p0) * CH);
        }
        {
            const float4* Vg = (const float4*)(V + kb);
#pragma unroll
            for (int it = 0; it < 4; ++it) {
                const int u = tid + it * 256, kp = u & 63, dq = u >> 6;
                float4 za = make_float4(0.f, 0.f, 0.f, 0.f), zb = za;
                if (2 * kp < nst) { za = Vg[(2 * kp) * 16 + dq]; zb = Vg[(2 * kp + 1) * 16 + dq]; }
                va[it] = za; vb[it] = zb;
            }
        }

        // ---- convert Q frags; issue Q prefetch (qr freed) ----
        const half8 a0 = mk8(qr[0], qr[1]);
        const half8 a1 = mk8(qr[2], qr[3]);
        {
            const float4* Qg4 = (const float4*)(Q + qb) + (long long)(wav * 16 + col) * 16;
            qr[0] = Qg4[quad * 2];     qr[1] = Qg4[quad * 2 + 1];
            qr[2] = Qg4[8 + quad * 2]; qr[3] = Qg4[9 + quad * 2];
        }

        // ---- QK^T: wave w covers rel keys [16w, 16w+80) -> 5 n-tiles ----
        f32x4 acc[5];
#pragma unroll
        for (int s = 0; s < 5; ++s) acc[s] = (f32x4){0.f, 0.f, 0.f, 0.f};
#pragma unroll
        for (int s = 0; s < 5; ++s) {
            const half8 b0 = mk8(kf[s][0], kf[s][1]);
            const half8 b1 = mk8(kf[s][2], kf[s][3]);
            acc[s] = __builtin_amdgcn_mfma_f32_16x16x32_f16(a0, b0, acc[s], 0, 0, 0);
            acc[s] = __builtin_amdgcn_mfma_f32_16x16x32_f16(a1, b1, acc[s], 0, 0, 0);
        }

        // ---- issue K prefetch (kf freed by QK) ----
        {
            const float4* Kg4 = (const float4*)(K + kb);
#pragma unroll
            for (int s = 0; s < 5; ++s) {
                const int krel = (wav + s) * 16 + col;
                const float4* Kr = Kg4 + ((krel < nst) ? krel : (nst - 1)) * 16;
                kf[s][0] = Kr[quad * 2];     kf[s][1] = Kr[quad * 2 + 1];
                kf[s][2] = Kr[8 + quad * 2]; kf[s][3] = Kr[9 + quad * 2];
            }
        }

        // ---- dual softmax (masks use nst_c) ----
#pragma unroll
        for (int r = 0; r < 4; ++r) {
            const int q   = wav * 16 + quad * 4 + r;
            const int kr0 = (q >> 3) * 8;
            const int kmx = min(kr0 + 72, nst_c);

            float tv[5]; bool vl[5];
            float mp = -1e30f, mn = -1e30f;
#pragma unroll
            for (int s = 0; s < 5; ++s) {
                const int c = (wav + s) * 16 + col;
                tv[s] = scale * acc[s][r];
                vl[s] = (c >= kr0) && (c < kmx);
                mp = fmaxf(mp, vl[s] ?  tv[s] : -1e30f);
                mn = fmaxf(mn, vl[s] ? -tv[s] : -1e30f);
            }
#pragma unroll
            for (int off = 1; off < 16; off <<= 1) {
                mp = fmaxf(mp, __shfl_xor(mp, off));
                mn = fmaxf(mn, __shfl_xor(mn, off));
            }
            float ep[5], en[5], sp = 0.f, sn = 0.f;
#pragma unroll
            for (int s = 0; s < 5; ++s) {
                ep[s] = vl[s] ? __expf( tv[s] - mp) : 0.f;
                en[s] = vl[s] ? __expf(-tv[s] - mn) : 0.f;
                sp += ep[s]; sn += en[s];
            }
#pragma unroll
            for (int off = 1; off < 16; off <<= 1) {
                sp += __shfl_xor(sp, off);
                sn += __shfl_xor(sn, off);
            }
            const float rp = (sp > 0.f) ? 1.f / sp : 0.f;
            const float rn = (sn > 0.f) ? 1.f / sn : 0.f;
#pragma unroll
            for (int s = 0; s < 5; ++s) {
                const float A = ep[s] * rp - en[s] * rn;   // invalid -> exact 0
                sP[q * PSTR + s * 16 + col] = (unsigned short)pk(A, A);
            }
        }

        __syncthreads();   // sVt[buf] ready for all waves (prefetch loads keep flying)

        // ---- PV: O[16x64] = P[16x96] * Vt^T ----
        f32x4 oc[4];
#pragma unroll
        for (int s = 0; s < 4; ++s) oc[s] = (f32x4){0.f, 0.f, 0.f, 0.f};
#pragma unroll
        for (int kq = 0; kq < 3; ++kq) {
            const half8 ap = ld8(&sP[(wav * 16 + col) * PSTR + kq * 32 + quad * 8]);
            const int kbx = wav * 16 + kq * 32 + quad * 8;
            const int kcl = (kbx <= 120) ? kbx : 120;      // clamped lanes have P==0
#pragma unroll
            for (int s = 0; s < 4; ++s) {
                const half8 bv = ld8(&vt[(s * 16 + col) * VSTR + kcl]);
                oc[s] = __builtin_amdgcn_mfma_f32_16x16x32_f16(ap, bv, oc[s], 0, 0, 0);
            }
        }

        float* Ob = O + qb_c;
#pragma unroll
        for (int s = 0; s < 4; ++s) {
#pragma unroll
            for (int r = 0; r < 4; ++r) {
                Ob[(wav * 16 + quad * 4 + r) * D + s * 16 + col] = oc[s][r];
            }
        }

        buf ^= 1;
        tile = nxt;
    }
}

extern "C" void kernel_launch(void* const* d_in, const int* in_sizes, int n_in,
                              void* d_out, int out_size, void* d_ws, size_t ws_size,
                              hipStream_t stream) {
    const float* Q  = (const float*)d_in[0];
    const float* K  = (const float*)d_in[1];
    const float* V  = (const float*)d_in[2];
    const float* ls = (const float*)d_in[3];
    float* O = (float*)d_out;

    const int L = 1024;
    const int nBH = in_sizes[0] / (L * D);    // B*H = 32
    dim3 grid(nBH * (NPATCH / G) / TPB);      // 512 persistent blocks x 8 tiles
    signed_attn_kernel<<<grid, 256, 0, stream>>>(Q, K, V, ls, O);
}

// Round 14
// 85.680 us; speedup vs baseline: 1.3326x; 1.3326x over previous
//
#include <hip/hip_runtime.h>
#include <math.h>

#define NPATCH 128
#define CH 8              // channels per patch = L / N_PATCHES
#define D 64
#define G 8               // query patches per tile
#define NQ (G*CH)         // 64 queries/tile
#define NKEY 128          // key-window slots per tile
#define VSTR 136          // f16 strides: ≡ 4 (mod 8) dwords -> 2-way max aliasing
#define PSTR 100          // per-wave-relative P row: 96 keys + pad
#define TPB 2             // tiles per persistent block -> grid = 512/TPB = 256 = 1 block/CU

typedef __fp16 half8 __attribute__((ext_vector_type(8)));
typedef float  f32x4 __attribute__((ext_vector_type(4)));
typedef unsigned u32x4 __attribute__((ext_vector_type(4)));

static __device__ __forceinline__ unsigned pk(float x, float y) {
    return __builtin_bit_cast(unsigned, __builtin_amdgcn_cvt_pkrtz(x, y));
}
static __device__ __forceinline__ half8 ld8(const unsigned short* p) {
    return __builtin_bit_cast(half8, *(const u32x4*)p);
}
static __device__ __forceinline__ half8 mk8(const float4& a, const float4& b) {
    u32x4 u = { pk(a.x, a.y), pk(a.z, a.w), pk(b.x, b.y), pk(b.z, b.w) };
    return __builtin_bit_cast(half8, u);
}

__global__ __launch_bounds__(256) void signed_attn_kernel(
    const float* __restrict__ Q, const float* __restrict__ K,
    const float* __restrict__ V, const float* __restrict__ logscale,
    float* __restrict__ O)
{
    __shared__ __align__(16) unsigned short sVt[2][D * VSTR]; // 2 x 17408 B (double buffer)
    __shared__ __align__(16) unsigned short sP[NQ * PSTR];    // 12800 B (wave-private rows)

    const int tid = threadIdx.x;
    const int wav = tid >> 6, lane = tid & 63;
    const int col = lane & 15, quad = lane >> 4;

    const float scale = fminf(fmaxf(__expf(logscale[0]), 1.0f), 30.0f) * 0.125f;

    // zero sP pad (rel cols 80..95) once; softmax only writes cols 0..79
#pragma unroll
    for (int r = 0; r < 4; ++r) {
        const int q = wav * 16 + quad * 4 + r;
        sP[q * PSTR + 80 + col] = 0;
    }

    int tile = blockIdx.x * TPB;              // 2 consecutive tiles (50% K/V window overlap)

    long long qb, kb; int nst;
    {
        const int bh = tile >> 4, p0 = (tile & 15) * G;
        const long long base = (long long)bh * (NPATCH * CH) * D;
        qb = base + (long long)(p0 * CH) * D;
        kb = base + (long long)((p0 + 1) * CH) * D;
        nst = min(NKEY, (NPATCH - 1 - p0) * CH);
    }

    float4 qr[4], kf[5][4], va[4], vb[4];

    // ---- head: issue tile-0 loads ----
    {
        const float4* Qg4 = (const float4*)(Q + qb) + (long long)(wav * 16 + col) * 16;
        qr[0] = Qg4[quad * 2];     qr[1] = Qg4[quad * 2 + 1];
        qr[2] = Qg4[8 + quad * 2]; qr[3] = Qg4[9 + quad * 2];
        const float4* Kg4 = (const float4*)(K + kb);
#pragma unroll
        for (int t = 0; t < 5; ++t) {
            const int krel = (wav + t) * 16 + col;
            const float4* Kr = Kg4 + ((krel < nst) ? krel : (nst - 1)) * 16;
            kf[t][0] = Kr[quad * 2];     kf[t][1] = Kr[quad * 2 + 1];
            kf[t][2] = Kr[8 + quad * 2]; kf[t][3] = Kr[9 + quad * 2];
        }
        const float4* Vg = (const float4*)(V + kb);
#pragma unroll
        for (int it = 0; it < 4; ++it) {
            const int u = tid + it * 256, kp = u & 63, dq = u >> 6;
            va[it] = make_float4(0.f, 0.f, 0.f, 0.f); vb[it] = va[it];
            if (2 * kp < nst) { va[it] = Vg[(2 * kp) * 16 + dq]; vb[it] = Vg[(2 * kp + 1) * 16 + dq]; }
        }
    }

    int buf = 0;
    for (int t = 0; t < TPB; ++t) {
        const long long qb_c = qb;
        const int nst_c = nst;
        const bool more = (t + 1 < TPB);

        // ---- 1. V regs (landed) -> sVt[buf] ----
        unsigned short* vt = sVt[buf];
#pragma unroll
        for (int it = 0; it < 4; ++it) {
            const int u = tid + it * 256, kp = u & 63, dq = u >> 6;
            *(unsigned*)&vt[(dq * 4 + 0) * VSTR + 2 * kp] = pk(va[it].x, vb[it].x);
            *(unsigned*)&vt[(dq * 4 + 1) * VSTR + 2 * kp] = pk(va[it].y, vb[it].y);
            *(unsigned*)&vt[(dq * 4 + 2) * VSTR + 2 * kp] = pk(va[it].z, vb[it].z);
            *(unsigned*)&vt[(dq * 4 + 3) * VSTR + 2 * kp] = pk(va[it].w, vb[it].w);
        }

        // ---- next-tile bookkeeping; V prefetch (va/vb just freed) ----
        if (more) {
            const int nxt = tile + 1;
            const int bh = nxt >> 4, p0 = (nxt & 15) * G;
            const long long base = (long long)bh * (NPATCH * CH) * D;
            qb = base + (long long)(p0 * CH) * D;
            kb = base + (long long)((p0 + 1) * CH) * D;
            nst = min(NKEY, (NPATCH - 1 - p0) * CH);
            tile = nxt;
            const float4* Vg = (const float4*)(V + kb);
#pragma unroll
            for (int it = 0; it < 4; ++it) {
                const int u = tid + it * 256, kp = u & 63, dq = u >> 6;
                float4 za = make_float4(0.f, 0.f, 0.f, 0.f), zb = za;
                if (2 * kp < nst) { za = Vg[(2 * kp) * 16 + dq]; zb = Vg[(2 * kp + 1) * 16 + dq]; }
                va[it] = za; vb[it] = zb;
            }
        }

        // ---- convert Q frags; Q prefetch (qr freed) ----
        const half8 a0 = mk8(qr[0], qr[1]);
        const half8 a1 = mk8(qr[2], qr[3]);
        if (more) {
            const float4* Qg4 = (const float4*)(Q + qb) + (long long)(wav * 16 + col) * 16;
            qr[0] = Qg4[quad * 2];     qr[1] = Qg4[quad * 2 + 1];
            qr[2] = Qg4[8 + quad * 2]; qr[3] = Qg4[9 + quad * 2];
        }

        // ---- QK^T: wave w covers rel keys [16w, 16w+80) -> 5 n-tiles ----
        f32x4 acc[5];
#pragma unroll
        for (int s = 0; s < 5; ++s) acc[s] = (f32x4){0.f, 0.f, 0.f, 0.f};
#pragma unroll
        for (int s = 0; s < 5; ++s) {
            const half8 b0 = mk8(kf[s][0], kf[s][1]);
            const half8 b1 = mk8(kf[s][2], kf[s][3]);
            acc[s] = __builtin_amdgcn_mfma_f32_16x16x32_f16(a0, b0, acc[s], 0, 0, 0);
            acc[s] = __builtin_amdgcn_mfma_f32_16x16x32_f16(a1, b1, acc[s], 0, 0, 0);
        }

        // ---- K prefetch (kf freed by QK) ----
        if (more) {
            const float4* Kg4 = (const float4*)(K + kb);
#pragma unroll
            for (int s = 0; s < 5; ++s) {
                const int krel = (wav + s) * 16 + col;
                const float4* Kr = Kg4 + ((krel < nst) ? krel : (nst - 1)) * 16;
                kf[s][0] = Kr[quad * 2];     kf[s][1] = Kr[quad * 2 + 1];
                kf[s][2] = Kr[8 + quad * 2]; kf[s][3] = Kr[9 + quad * 2];
            }
        }

        // ---- dual softmax (masks use nst_c) ----
#pragma unroll
        for (int r = 0; r < 4; ++r) {
            const int q   = wav * 16 + quad * 4 + r;
            const int kr0 = (q >> 3) * 8;
            const int kmx = min(kr0 + 72, nst_c);

            float tv[5]; bool vl[5];
            float mp = -1e30f, mn = -1e30f;
#pragma unroll
            for (int s = 0; s < 5; ++s) {
                const int c = (wav + s) * 16 + col;
                tv[s] = scale * acc[s][r];
                vl[s] = (c >= kr0) && (c < kmx);
                mp = fmaxf(mp, vl[s] ?  tv[s] : -1e30f);
                mn = fmaxf(mn, vl[s] ? -tv[s] : -1e30f);
            }
#pragma unroll
            for (int off = 1; off < 16; off <<= 1) {
                mp = fmaxf(mp, __shfl_xor(mp, off));
                mn = fmaxf(mn, __shfl_xor(mn, off));
            }
            float ep[5], en[5], sp = 0.f, sn = 0.f;
#pragma unroll
            for (int s = 0; s < 5; ++s) {
                ep[s] = vl[s] ? __expf( tv[s] - mp) : 0.f;
                en[s] = vl[s] ? __expf(-tv[s] - mn) : 0.f;
                sp += ep[s]; sn += en[s];
            }
#pragma unroll
            for (int off = 1; off < 16; off <<= 1) {
                sp += __shfl_xor(sp, off);
                sn += __shfl_xor(sn, off);
            }
            const float rp = (sp > 0.f) ? 1.f / sp : 0.f;
            const float rn = (sn > 0.f) ? 1.f / sn : 0.f;
#pragma unroll
            for (int s = 0; s < 5; ++s) {
                const float A = ep[s] * rp - en[s] * rn;   // invalid -> exact 0
                sP[q * PSTR + s * 16 + col] = (unsigned short)pk(A, A);
            }
        }

        __syncthreads();   // sVt[buf] ready for all waves

        // ---- PV: O[16x64] = P[16x96] * Vt^T ----
        f32x4 oc[4];
#pragma unroll
        for (int s = 0; s < 4; ++s) oc[s] = (f32x4){0.f, 0.f, 0.f, 0.f};
#pragma unroll
        for (int kq = 0; kq < 3; ++kq) {
            const half8 ap = ld8(&sP[(wav * 16 + col) * PSTR + kq * 32 + quad * 8]);
            const int kbx = wav * 16 + kq * 32 + quad * 8;
            const int kcl = (kbx <= 120) ? kbx : 120;      // clamped lanes have P==0
#pragma unroll
            for (int s = 0; s < 4; ++s) {
                const half8 bv = ld8(&vt[(s * 16 + col) * VSTR + kcl]);
                oc[s] = __builtin_amdgcn_mfma_f32_16x16x32_f16(ap, bv, oc[s], 0, 0, 0);
            }
        }

        float* Ob = O + qb_c;
#pragma unroll
        for (int s = 0; s < 4; ++s) {
#pragma unroll
            for (int r = 0; r < 4; ++r) {
                Ob[(wav * 16 + quad * 4 + r) * D + s * 16 + col] = oc[s][r];
            }
        }

        buf ^= 1;
    }
}

extern "C" void kernel_launch(void* const* d_in, const int* in_sizes, int n_in,
                              void* d_out, int out_size, void* d_ws, size_t ws_size,
                              hipStream_t stream) {
    const float* Q  = (const float*)d_in[0];
    const float* K  = (const float*)d_in[1];
    const float* V  = (const float*)d_in[2];
    const float* ls = (const float*)d_in[3];
    float* O = (float*)d_out;

    const int L = 1024;
    const int nBH = in_sizes[0] / (L * D);    // B*H = 32
    dim3 grid(nBH * (NPATCH / G) / TPB);      // 256 persistent blocks x 2 tiles = 1/CU
    signed_attn_kernel<<<grid, 256, 0, stream>>>(Q, K, V, ls, O);
}